// Round 12
// baseline (35.334 us; speedup 1.0000x reference)
//
#include <hip/hip_runtime.h>
#include <math.h>

#define BINS 30
// ---- fast path: 512 WGs x 512 threads (2 WG/CU), 64 elems/thread, N = 2^24 ----
#define FGRID 512
#define FBLOCK 512
#define FITERS 16                       // float4 iterations per thread
#define DEPTH 8                         // load pairs in flight
#define FNCOPIES 128                    // 8 waves * 16 copies
#define VSTEP (FGRID * FBLOCK * 16)     // byte stride between iterations (4 MB)
// ---- generic fallback ----
#define GGRID 2048
#define GBLOCK 256
#define GNCOPIES 64
#define CPW 16                          // copies per wave (lane & 15)
#define CSTRIDE 31                      // 30 bins + 1 pad word (bank stagger)
// packed u32 payload: count bits 21..31 (+2/elem), sum(g) bits 0..20 (0.12 fx)
#define GSCALE 4096.0f
#define CNT_SHIFT 21
#define CNT_ONE (2u << CNT_SHIFT)
#define GMASK 0x1FFFFFu

// fast-path d_ws layout: u32 cnt_part[FGRID][BINS] ; f32 gs_part[FGRID][BINS]
// fallback d_ws layout:  u32 g_cnt[BINS] ; f32 g_gsum[BINS]

__device__ __forceinline__ void ghmc_elem(float p, int t, unsigned int* s_hist,
                                          unsigned int copy_base)
{
    // g = |sigmoid(p) - t| = sigmoid(t ? -p : p)
    float q = __int_as_float(__float_as_int(p) ^ (t << 31));
    float e = __expf(-q);
    float g = __builtin_amdgcn_rcpf(1.0f + e);
    int b = min((int)(g * 30.0f), BINS - 1);
    unsigned int pkt = CNT_ONE | (unsigned int)(g * GSCALE);
    atomicAdd(&s_hist[copy_base + b], pkt);
}

__device__ __forceinline__ void ghmc_vec4(float4 p, int4 t, unsigned int* s_hist,
                                          unsigned int copy_base)
{
    ghmc_elem(p.x, t.x, s_hist, copy_base);
    ghmc_elem(p.y, t.y, s_hist, copy_base);
    ghmc_elem(p.z, t.z, s_hist, copy_base);
    ghmc_elem(p.w, t.w, s_hist, copy_base);
}

// ---------------- fast path: asm-load pipeline, depth 8, counted vmcnt ----------------
__global__ __launch_bounds__(FBLOCK) void ghmc_pass1_big(
    const float* __restrict__ pred, const int* __restrict__ target,
    unsigned int* __restrict__ cnt_part, float* __restrict__ gs_part)
{
    __shared__ unsigned int s_hist[FNCOPIES * CSTRIDE];
    const int tid = threadIdx.x;
    const unsigned int copy_base = (((tid >> 6) << 4) + (tid & (CPW - 1))) * CSTRIDE;

    for (int i = tid; i < FNCOPIES * CSTRIDE; i += FBLOCK) s_hist[i] = 0u;
    __syncthreads();

    const unsigned int voff0 = (unsigned int)((blockIdx.x * FBLOCK + tid) * 16);

    float4 pb[DEPTH];
    int4   tb[DEPTH];

    // asm loads are opaque to the scheduler -> cannot be flattened or sunk;
    // vmcnt counted manually (never drained to 0 in steady state).
#define ISSUE(k)                                                                 \
    do {                                                                         \
        asm volatile("global_load_dwordx4 %0, %1, %2"                            \
                     : "=v"(pb[(k) & (DEPTH - 1)])                               \
                     : "v"(voff0 + (unsigned)(k) * (unsigned)VSTEP), "s"(pred)); \
        asm volatile("global_load_dwordx4 %0, %1, %2"                            \
                     : "=v"(tb[(k) & (DEPTH - 1)])                               \
                     : "v"(voff0 + (unsigned)(k) * (unsigned)VSTEP), "s"(target)); \
    } while (0)

    ISSUE(0); ISSUE(1); ISSUE(2); ISSUE(3); ISSUE(4); ISSUE(5); ISSUE(6);

    #pragma unroll
    for (int k = 0; k < FITERS; ++k) {
        if (k + DEPTH - 1 < FITERS) ISSUE(k + DEPTH - 1);
        // steady state: pairs k..k+7 in flight (16 loads); wait until pair k done.
        asm volatile("s_waitcnt vmcnt(%0)"
                     :: "i"((k + DEPTH - 1 < FITERS) ? 2 * (DEPTH - 1)
                                                     : 2 * (FITERS - 1 - k)));
        __builtin_amdgcn_sched_barrier(0);   // rule #18: nothing hoists past the wait
        ghmc_vec4(pb[k & (DEPTH - 1)], tb[k & (DEPTH - 1)], s_hist, copy_base);
    }
#undef ISSUE

    __syncthreads();
    // flush: 16 lanes per bin, 8 copies each; shfl reduce; no atomics
    {
        const int bin = tid >> 4;            // 0..31 (30,31 idle)
        const int j   = tid & 15;
        if (bin < BINS) {
            unsigned int c = 0, g = 0;
            #pragma unroll
            for (int jj = 0; jj < 8; ++jj) {
                unsigned int v = s_hist[(j * 8 + jj) * CSTRIDE + bin];
                c += v >> CNT_SHIFT;
                g += v & GMASK;
            }
            #pragma unroll
            for (int off = 8; off > 0; off >>= 1) {
                c += __shfl_xor(c, off);
                g += __shfl_xor(g, off);
            }
            if (j == 0) {
                cnt_part[blockIdx.x * BINS + bin] = c;
                gs_part [blockIdx.x * BINS + bin] = (float)g * (1.0f / GSCALE);
            }
        }
    }
}

// parallel partial-reduce + closing math: 32 threads per bin
__global__ __launch_bounds__(1024) void ghmc_final_part(
    const unsigned int* __restrict__ cnt_part, const float* __restrict__ gs_part,
    const float* __restrict__ acc_sum, float* __restrict__ out, float total, int nwg)
{
    __shared__ unsigned int s_cnt[32];
    __shared__ float        s_gs[32];
    const int tid = threadIdx.x;
    const int bin = tid >> 5;               // 32 threads per bin; groups 30,31 idle
    const int j   = tid & 31;

    unsigned int c = 0;
    float        g = 0.0f;
    if (bin < BINS) {
        for (int w = j; w < nwg; w += 32) {
            c += cnt_part[w * BINS + bin];
            g += gs_part [w * BINS + bin];
        }
    }
    #pragma unroll
    for (int off = 16; off > 0; off >>= 1) {
        c += __shfl_xor(c, off);
        g += __shfl_xor(g, off);
    }
    if (bin < BINS && j == 0) { s_cnt[bin] = c; s_gs[bin] = g; }
    __syncthreads();

    if (tid < 64) {                          // closing math on wave 0
        bool nonempty = (tid < BINS) && (s_cnt[tid] > 0u);
        float nb = fmaxf((float)__popcll(__ballot(nonempty)), 1.0f);

        float val = 0.0f;
        if (nonempty) {
            float cc    = (float)s_cnt[tid];    // = 2 * elements (reference histogram)
            float elems = 0.5f * cc;
            float gmean = s_gs[tid] / elems;
            // two-channel bce per element collapses to F(g); evaluate at bin mean
            float F = log1pf(expf(gmean)) + log1pf(expf(1.0f - gmean)) - 1.0f + gmean;
            float new_acc = 0.75f * acc_sum[tid] + 0.25f * cc;
            float w = (total / fmaxf(new_acc, 1e-12f)) / nb;
            val = w * elems * F;
        }
        #pragma unroll
        for (int off = 32; off > 0; off >>= 1) val += __shfl_down(val, off);
        if (tid == 0) out[0] = val / total;
    }
}

// ---------------- generic fallback (any n) ----------------
__global__ __launch_bounds__(GBLOCK) void ghmc_pass1_gen(
    const float* __restrict__ pred, const int* __restrict__ target,
    unsigned int* __restrict__ g_cnt, float* __restrict__ g_gsum,
    int n4, int n)
{
    __shared__ unsigned int s_hist[GNCOPIES * CSTRIDE];
    const int tid = threadIdx.x;
    const unsigned int copy_base = (((tid >> 6) << 4) + (tid & (CPW - 1))) * CSTRIDE;
    for (int i = tid; i < GNCOPIES * CSTRIDE; i += GBLOCK) s_hist[i] = 0u;
    __syncthreads();

    const int gid    = blockIdx.x * GBLOCK + tid;
    const int stride = gridDim.x * GBLOCK;
    for (int i = gid; i < n4; i += stride) {
        float4 p = reinterpret_cast<const float4*>(pred)[i];
        int4   t = reinterpret_cast<const int4*>(target)[i];
        ghmc_vec4(p, t, s_hist, copy_base);
    }
    if (blockIdx.x == 0) {
        for (int i = n4 * 4 + tid; i < n; i += GBLOCK)
            ghmc_elem(pred[i], target[i], s_hist, copy_base);
    }

    __syncthreads();
    if (tid < BINS) {
        unsigned int cnt = 0;
        float gs = 0.0f;
        #pragma unroll
        for (int c = 0; c < GNCOPIES; ++c) {
            unsigned int v = s_hist[c * CSTRIDE + tid];
            cnt += v >> CNT_SHIFT;
            gs  += (float)(v & GMASK);
        }
        atomicAdd(&g_cnt[tid], cnt);
        atomicAdd(&g_gsum[tid], gs * (1.0f / GSCALE));
    }
}

__global__ __launch_bounds__(64) void ghmc_final_atomic(
    const unsigned int* __restrict__ counts, const float* __restrict__ gsums,
    const float* __restrict__ acc_sum, float* __restrict__ out, float total)
{
    const int tid = threadIdx.x;
    bool nonempty = (tid < BINS) && (counts[tid] > 0u);
    float nb = fmaxf((float)__popcll(__ballot(nonempty)), 1.0f);

    float val = 0.0f;
    if (nonempty) {
        float cc    = (float)counts[tid];
        float elems = 0.5f * cc;
        float gmean = gsums[tid] / elems;
        float F = log1pf(expf(gmean)) + log1pf(expf(1.0f - gmean)) - 1.0f + gmean;
        float new_acc = 0.75f * acc_sum[tid] + 0.25f * cc;
        float w = (total / fmaxf(new_acc, 1e-12f)) / nb;
        val = w * elems * F;
    }
    #pragma unroll
    for (int off = 32; off > 0; off >>= 1) val += __shfl_down(val, off);
    if (tid == 0) out[0] = val / total;
}

extern "C" void kernel_launch(void* const* d_in, const int* in_sizes, int n_in,
                              void* d_out, int out_size, void* d_ws, size_t ws_size,
                              hipStream_t stream) {
    const float* pred    = (const float*)d_in[0];
    const float* acc_sum = (const float*)d_in[1];
    const int*   target  = (const int*)d_in[2];
    float* out = (float*)d_out;

    int n = in_sizes[0];
    float total = fmaxf(2.0f * (float)n, 1.0f);

    const size_t fast_ws = (size_t)FGRID * BINS * 8;   // 122880 B
    if (n == FGRID * FBLOCK * FITERS * 4 && ws_size >= fast_ws) {
        unsigned int* cnt_part = (unsigned int*)d_ws;
        float*        gs_part  = (float*)((unsigned int*)d_ws + FGRID * BINS);
        ghmc_pass1_big<<<FGRID, FBLOCK, 0, stream>>>(pred, target, cnt_part, gs_part);
        ghmc_final_part<<<1, 1024, 0, stream>>>(cnt_part, gs_part, acc_sum, out, total, FGRID);
    } else {
        int n4 = n / 4;
        unsigned int* g_cnt  = (unsigned int*)d_ws;
        float*        g_gsum = (float*)d_ws + BINS;
        hipMemsetAsync(d_ws, 0, 2 * BINS * sizeof(float), stream);
        ghmc_pass1_gen<<<GGRID, GBLOCK, 0, stream>>>(pred, target, g_cnt, g_gsum, n4, n);
        ghmc_final_atomic<<<1, 64, 0, stream>>>(g_cnt, g_gsum, acc_sum, out, total);
    }
}

// Round 13
// 31.659 us; speedup vs baseline: 1.1161x; 1.1161x over previous
//
#include <hip/hip_runtime.h>
#include <math.h>

#define BINS 30
// ---- fast path: 256 WGs x 1024 threads, 64 elems/thread, N = 2^24 ----
#define FGRID 256
#define FBLOCK 1024
#define FITERS 16                       // float4 iterations per thread
#define DEPTH 4                         // load pairs in flight (r11 best)
#define FNCOPIES 256                    // 16 waves * 16 copies
#define VSTEP (FGRID * FBLOCK * 16)     // byte stride between iterations (4 MB)
// ---- generic fallback ----
#define GGRID 2048
#define GBLOCK 256
#define GNCOPIES 64
#define CPW 16                          // copies per wave (lane & 15)
#define CSTRIDE 31                      // 30 bins + 1 pad word (bank stagger)
// packed u32 payload: count bits 21..31 (+2/elem), sum(g) bits 0..20 (0.12 fx)
#define GSCALE 4096.0f
#define CNT_SHIFT 21
#define CNT_ONE (2u << CNT_SHIFT)
#define GMASK 0x1FFFFFu

// fast-path d_ws layout: u32 cnt_part[FGRID][BINS] ; f32 gs_part[FGRID][BINS]
// fallback d_ws layout:  u32 g_cnt[BINS] ; f32 g_gsum[BINS]

__device__ __forceinline__ void ghmc_elem(float p, int t, unsigned int* s_hist,
                                          unsigned int copy_base)
{
    // g = |sigmoid(p) - t| = sigmoid(t ? -p : p)
    float q = __int_as_float(__float_as_int(p) ^ (t << 31));
    float e = __expf(-q);
    float g = __builtin_amdgcn_rcpf(1.0f + e);
    int b = min((int)(g * 30.0f), BINS - 1);
    unsigned int pkt = CNT_ONE | (unsigned int)(g * GSCALE);
    atomicAdd(&s_hist[copy_base + b], pkt);
}

__device__ __forceinline__ void ghmc_vec4(float4 p, int4 t, unsigned int* s_hist,
                                          unsigned int copy_base)
{
    ghmc_elem(p.x, t.x, s_hist, copy_base);
    ghmc_elem(p.y, t.y, s_hist, copy_base);
    ghmc_elem(p.z, t.z, s_hist, copy_base);
    ghmc_elem(p.w, t.w, s_hist, copy_base);
}

// ---------------- fast path: asm-load pipeline, depth 4, counted vmcnt, nt ----------------
__global__ __launch_bounds__(FBLOCK) void ghmc_pass1_big(
    const float* __restrict__ pred, const int* __restrict__ target,
    unsigned int* __restrict__ cnt_part, float* __restrict__ gs_part)
{
    __shared__ unsigned int s_hist[FNCOPIES * CSTRIDE];
    const int tid = threadIdx.x;
    const unsigned int copy_base = (((tid >> 6) << 4) + (tid & (CPW - 1))) * CSTRIDE;

    for (int i = tid; i < FNCOPIES * CSTRIDE; i += FBLOCK) s_hist[i] = 0u;
    __syncthreads();

    const unsigned int voff0 = (unsigned int)((blockIdx.x * FBLOCK + tid) * 16);

    float4 pb[DEPTH];
    int4   tb[DEPTH];

    // asm loads are opaque to the scheduler -> cannot be flattened/sunk;
    // vmcnt counted manually; nt = non-temporal (don't allocate in L1).
#define ISSUE(k)                                                                 \
    do {                                                                         \
        asm volatile("global_load_dwordx4 %0, %1, %2 nt"                         \
                     : "=v"(pb[(k) & (DEPTH - 1)])                               \
                     : "v"(voff0 + (unsigned)(k) * (unsigned)VSTEP), "s"(pred)); \
        asm volatile("global_load_dwordx4 %0, %1, %2 nt"                         \
                     : "=v"(tb[(k) & (DEPTH - 1)])                               \
                     : "v"(voff0 + (unsigned)(k) * (unsigned)VSTEP), "s"(target)); \
    } while (0)

    ISSUE(0); ISSUE(1); ISSUE(2);

    #pragma unroll
    for (int k = 0; k < FITERS; ++k) {
        if (k + DEPTH - 1 < FITERS) ISSUE(k + DEPTH - 1);
        // steady state: pairs k..k+3 in flight (8 loads); wait until pair k done.
        asm volatile("s_waitcnt vmcnt(%0)"
                     :: "i"((k + DEPTH - 1 < FITERS) ? 2 * (DEPTH - 1)
                                                     : 2 * (FITERS - 1 - k)));
        __builtin_amdgcn_sched_barrier(0);   // rule #18: nothing hoists past the wait
        ghmc_vec4(pb[k & (DEPTH - 1)], tb[k & (DEPTH - 1)], s_hist, copy_base);
    }
#undef ISSUE

    __syncthreads();
    // flush: one 32-lane group per bin; 8 strided reads + shfl reduce; no atomics
    {
        const int bin   = tid >> 5;          // 0..31 (30,31 idle)
        const int chunk = tid & 31;          // 8 copies per chunk
        if (bin < BINS) {
            unsigned int c = 0, g = 0;
            #pragma unroll
            for (int j = 0; j < 8; ++j) {
                unsigned int v = s_hist[(chunk * 8 + j) * CSTRIDE + bin];
                c += v >> CNT_SHIFT;
                g += v & GMASK;
            }
            #pragma unroll
            for (int off = 16; off > 0; off >>= 1) {
                c += __shfl_xor(c, off);
                g += __shfl_xor(g, off);
            }
            if (chunk == 0) {
                cnt_part[blockIdx.x * BINS + bin] = c;
                gs_part [blockIdx.x * BINS + bin] = (float)g * (1.0f / GSCALE);
            }
        }
    }
}

// parallel partial-reduce + closing math: 32 threads per bin
__global__ __launch_bounds__(1024) void ghmc_final_part(
    const unsigned int* __restrict__ cnt_part, const float* __restrict__ gs_part,
    const float* __restrict__ acc_sum, float* __restrict__ out, float total, int nwg)
{
    __shared__ unsigned int s_cnt[32];
    __shared__ float        s_gs[32];
    const int tid = threadIdx.x;
    const int bin = tid >> 5;               // 32 threads per bin; groups 30,31 idle
    const int j   = tid & 31;

    unsigned int c = 0;
    float        g = 0.0f;
    if (bin < BINS) {
        for (int w = j; w < nwg; w += 32) {
            c += cnt_part[w * BINS + bin];
            g += gs_part [w * BINS + bin];
        }
    }
    #pragma unroll
    for (int off = 16; off > 0; off >>= 1) {
        c += __shfl_xor(c, off);
        g += __shfl_xor(g, off);
    }
    if (bin < BINS && j == 0) { s_cnt[bin] = c; s_gs[bin] = g; }
    __syncthreads();

    if (tid < 64) {                          // closing math on wave 0
        bool nonempty = (tid < BINS) && (s_cnt[tid] > 0u);
        float nb = fmaxf((float)__popcll(__ballot(nonempty)), 1.0f);

        float val = 0.0f;
        if (nonempty) {
            float cc    = (float)s_cnt[tid];    // = 2 * elements (reference histogram)
            float elems = 0.5f * cc;
            float gmean = s_gs[tid] / elems;
            // two-channel bce per element collapses to F(g); evaluate at bin mean
            float F = log1pf(expf(gmean)) + log1pf(expf(1.0f - gmean)) - 1.0f + gmean;
            float new_acc = 0.75f * acc_sum[tid] + 0.25f * cc;
            float w = (total / fmaxf(new_acc, 1e-12f)) / nb;
            val = w * elems * F;
        }
        #pragma unroll
        for (int off = 32; off > 0; off >>= 1) val += __shfl_down(val, off);
        if (tid == 0) out[0] = val / total;
    }
}

// ---------------- generic fallback (any n) ----------------
__global__ __launch_bounds__(GBLOCK) void ghmc_pass1_gen(
    const float* __restrict__ pred, const int* __restrict__ target,
    unsigned int* __restrict__ g_cnt, float* __restrict__ g_gsum,
    int n4, int n)
{
    __shared__ unsigned int s_hist[GNCOPIES * CSTRIDE];
    const int tid = threadIdx.x;
    const unsigned int copy_base = (((tid >> 6) << 4) + (tid & (CPW - 1))) * CSTRIDE;
    for (int i = tid; i < GNCOPIES * CSTRIDE; i += GBLOCK) s_hist[i] = 0u;
    __syncthreads();

    const int gid    = blockIdx.x * GBLOCK + tid;
    const int stride = gridDim.x * GBLOCK;
    for (int i = gid; i < n4; i += stride) {
        float4 p = reinterpret_cast<const float4*>(pred)[i];
        int4   t = reinterpret_cast<const int4*>(target)[i];
        ghmc_vec4(p, t, s_hist, copy_base);
    }
    if (blockIdx.x == 0) {
        for (int i = n4 * 4 + tid; i < n; i += GBLOCK)
            ghmc_elem(pred[i], target[i], s_hist, copy_base);
    }

    __syncthreads();
    if (tid < BINS) {
        unsigned int cnt = 0;
        float gs = 0.0f;
        #pragma unroll
        for (int c = 0; c < GNCOPIES; ++c) {
            unsigned int v = s_hist[c * CSTRIDE + tid];
            cnt += v >> CNT_SHIFT;
            gs  += (float)(v & GMASK);
        }
        atomicAdd(&g_cnt[tid], cnt);
        atomicAdd(&g_gsum[tid], gs * (1.0f / GSCALE));
    }
}

__global__ __launch_bounds__(64) void ghmc_final_atomic(
    const unsigned int* __restrict__ counts, const float* __restrict__ gsums,
    const float* __restrict__ acc_sum, float* __restrict__ out, float total)
{
    const int tid = threadIdx.x;
    bool nonempty = (tid < BINS) && (counts[tid] > 0u);
    float nb = fmaxf((float)__popcll(__ballot(nonempty)), 1.0f);

    float val = 0.0f;
    if (nonempty) {
        float cc    = (float)counts[tid];
        float elems = 0.5f * cc;
        float gmean = gsums[tid] / elems;
        float F = log1pf(expf(gmean)) + log1pf(expf(1.0f - gmean)) - 1.0f + gmean;
        float new_acc = 0.75f * acc_sum[tid] + 0.25f * cc;
        float w = (total / fmaxf(new_acc, 1e-12f)) / nb;
        val = w * elems * F;
    }
    #pragma unroll
    for (int off = 32; off > 0; off >>= 1) val += __shfl_down(val, off);
    if (tid == 0) out[0] = val / total;
}

extern "C" void kernel_launch(void* const* d_in, const int* in_sizes, int n_in,
                              void* d_out, int out_size, void* d_ws, size_t ws_size,
                              hipStream_t stream) {
    const float* pred    = (const float*)d_in[0];
    const float* acc_sum = (const float*)d_in[1];
    const int*   target  = (const int*)d_in[2];
    float* out = (float*)d_out;

    int n = in_sizes[0];
    float total = fmaxf(2.0f * (float)n, 1.0f);

    const size_t fast_ws = (size_t)FGRID * BINS * 8;   // 61440 B
    if (n == FGRID * FBLOCK * FITERS * 4 && ws_size >= fast_ws) {
        unsigned int* cnt_part = (unsigned int*)d_ws;
        float*        gs_part  = (float*)((unsigned int*)d_ws + FGRID * BINS);
        ghmc_pass1_big<<<FGRID, FBLOCK, 0, stream>>>(pred, target, cnt_part, gs_part);
        ghmc_final_part<<<1, 1024, 0, stream>>>(cnt_part, gs_part, acc_sum, out, total, FGRID);
    } else {
        int n4 = n / 4;
        unsigned int* g_cnt  = (unsigned int*)d_ws;
        float*        g_gsum = (float*)d_ws + BINS;
        hipMemsetAsync(d_ws, 0, 2 * BINS * sizeof(float), stream);
        ghmc_pass1_gen<<<GGRID, GBLOCK, 0, stream>>>(pred, target, g_cnt, g_gsum, n4, n);
        ghmc_final_atomic<<<1, 64, 0, stream>>>(g_cnt, g_gsum, acc_sum, out, total);
    }
}